// Round 1
// baseline (407.748 us; speedup 1.0000x reference)
//
#include <hip/hip_runtime.h>
#include <math.h>

#define NTOT 33554432
#define CS 64
#define REF 16
#define HID 64
#define NC (NTOT / CS)

// ws layout (floats):
//   [0,1024)     ga[j][k]    = w_g1[j][k] + w_g1[j][32+k]      (ea coefficient)
//   [1024,2048)  gb[j][k]    = w_g1[j][16+k] - w_g1[j][32+k]   (eb coefficient)
//   [2048,3072)  gp[j][k]    = w_g1[j][48+k]                   (ea*eb coefficient)
//   [3072,4096)  wc1c[j][k]  = w_c1[j][k] + w_c1[j][32+k]      (enc coefficient)
//   [4096,4160)  refc_p[j]   = b_c1[j] + sum_k ref_policy[k]*(w_c1[j][16+k]-w_c1[j][32+k])
//   [4160,4224)  refc_m[j]   = same with ref_meta
//   [4224,8320)  w_c2T[j][i] = w_c2[i][j]
#define WS_FLOATS 8320

#if defined(__has_builtin)
#if __has_builtin(__builtin_amdgcn_rcpf)
#define FAST_RCP(x) __builtin_amdgcn_rcpf(x)
#endif
#endif
#ifndef FAST_RCP
#define FAST_RCP(x) (1.0f / (x))
#endif

__device__ __forceinline__ float fast_tanh(float x) {
  // tanh(x) = 1 - 2/(exp(2x)+1); exp overflow/underflow saturates correctly.
  float e = __expf(2.0f * x);
  return 1.0f - 2.0f * FAST_RCP(e + 1.0f);
}

__device__ __forceinline__ float get4(const float4& v, int c) {
  return c == 0 ? v.x : c == 1 ? v.y : c == 2 ? v.z : v.w;
}

__global__ void setup_fold_kernel(const float* __restrict__ w_g1,
                                  const float* __restrict__ w_c1,
                                  const float* __restrict__ b_c1,
                                  const float* __restrict__ w_c2,
                                  const float* __restrict__ ref_p,
                                  const float* __restrict__ ref_m,
                                  float* __restrict__ ws) {
  const int t = threadIdx.x;  // single block of 256
  for (int idx = t; idx < 1024; idx += 256) {
    const int j = idx >> 4, k = idx & 15;
    ws[idx]        = w_g1[j * 64 + k] + w_g1[j * 64 + 32 + k];
    ws[1024 + idx] = w_g1[j * 64 + 16 + k] - w_g1[j * 64 + 32 + k];
    ws[2048 + idx] = w_g1[j * 64 + 48 + k];
    ws[3072 + idx] = w_c1[j * 48 + k] + w_c1[j * 48 + 32 + k];
  }
  if (t < 64) {
    float sp = b_c1[t], sm = b_c1[t];
    for (int k = 0; k < REF; ++k) {
      const float wd = w_c1[t * 48 + 16 + k] - w_c1[t * 48 + 32 + k];
      sp += ref_p[k] * wd;
      sm += ref_m[k] * wd;
    }
    ws[4096 + t] = sp;
    ws[4160 + t] = sm;
  }
  for (int idx = t; idx < 4096; idx += 256) {
    const int j = idx >> 6, i = idx & 63;
    ws[4224 + idx] = w_c2[i * 64 + j];
  }
}

template <bool USE_WS>
__global__ __launch_bounds__(256) void dual_mutate_kernel(
    const float* __restrict__ A, const float* __restrict__ B,
    const int* __restrict__ coords, const float* __restrict__ noise,
    const float* __restrict__ w_enc, const float* __restrict__ b_enc,
    const float* __restrict__ w_c1, const float* __restrict__ b_c1,
    const float* __restrict__ w_c2, const float* __restrict__ b_c2,
    const float* __restrict__ w_g1, const float* __restrict__ b_g1,
    const float* __restrict__ w_g2, const float* __restrict__ b_g2,
    const float* __restrict__ ref_p, const float* __restrict__ ref_m,
    const float* __restrict__ cs_p, const float* __restrict__ cs_m,
    const float* __restrict__ es_p, const float* __restrict__ es_m,
    const float* __restrict__ ws, float* __restrict__ out) {
  const int chunk = blockIdx.x * blockDim.x + threadIdx.x;
  if (chunk >= NC) return;
  const size_t off = (size_t)chunk * CS;
  const float* ap = A + off;
  const float* bp = B + off;

  // ---------------- Phase A: ea = tanh(a @ w_enc^T + b_enc), eb likewise ----
  float ea[REF], eb[REF];
#pragma unroll
  for (int j = 0; j < REF; ++j) {
    const float bj = b_enc[j];
    ea[j] = bj;
    eb[j] = bj;
  }
#pragma unroll 4
  for (int k4 = 0; k4 < CS / 4; ++k4) {
    const float4 a4 = *reinterpret_cast<const float4*>(ap + 4 * k4);
    const float4 b4 = *reinterpret_cast<const float4*>(bp + 4 * k4);
#pragma unroll
    for (int c = 0; c < 4; ++c) {
      const float av = get4(a4, c);
      const float bv = get4(b4, c);
      const int k = 4 * k4 + c;
#pragma unroll
      for (int j = 0; j < REF; ++j) {
        const float w = w_enc[j * CS + k];  // uniform -> s_load
        ea[j] = fmaf(av, w, ea[j]);
        eb[j] = fmaf(bv, w, eb[j]);
      }
    }
  }
#pragma unroll
  for (int j = 0; j < REF; ++j) {
    ea[j] = fast_tanh(ea[j]);
    eb[j] = fast_tanh(eb[j]);
  }

  // ---------------- Gate: alpha = sigmoid(l0 - l1) --------------------------
  float pp[REF], dd[REF];
#pragma unroll
  for (int j = 0; j < REF; ++j) {
    pp[j] = ea[j] * eb[j];
    dd[j] = ea[j] - eb[j];
  }
  float l0 = b_g2[0], l1 = b_g2[1];
#pragma unroll 2
  for (int j = 0; j < HID; ++j) {
    float acc = b_g1[j];
    if (USE_WS) {
#pragma unroll
      for (int k = 0; k < REF; ++k) {
        acc = fmaf(ea[k], ws[j * REF + k], acc);
        acc = fmaf(eb[k], ws[1024 + j * REF + k], acc);
        acc = fmaf(pp[k], ws[2048 + j * REF + k], acc);
      }
    } else {
#pragma unroll
      for (int k = 0; k < REF; ++k) {
        acc = fmaf(ea[k], w_g1[j * 64 + k], acc);
        acc = fmaf(eb[k], w_g1[j * 64 + 16 + k], acc);
        acc = fmaf(dd[k], w_g1[j * 64 + 32 + k], acc);
        acc = fmaf(pp[k], w_g1[j * 64 + 48 + k], acc);
      }
    }
    const float h = fast_tanh(acc);
    l0 = fmaf(w_g2[j], h, l0);
    l1 = fmaf(w_g2[HID + j], h, l1);
  }
  const float alpha = FAST_RCP(1.0f + __expf(l1 - l0));

  // ---------------- Phase B: base + enc(base) -------------------------------
  const int split = coords[0];
  const bool policy = (chunk * CS) < split;

  float base[CS];
  float enc[REF];
#pragma unroll
  for (int j = 0; j < REF; ++j) enc[j] = b_enc[j];
#pragma unroll
  for (int k4 = 0; k4 < CS / 4; ++k4) {
    const float4 a4 = *reinterpret_cast<const float4*>(ap + 4 * k4);
    const float4 b4 = *reinterpret_cast<const float4*>(bp + 4 * k4);
#pragma unroll
    for (int c = 0; c < 4; ++c) {
      const int k = 4 * k4 + c;
      const float av = get4(a4, c);
      const float bv = get4(b4, c);
      const float bb = fmaf(alpha, av - bv, bv);  // alpha*a + (1-alpha)*b
      base[k] = bb;
#pragma unroll
      for (int j = 0; j < REF; ++j) enc[j] = fmaf(bb, w_enc[j * CS + k], enc[j]);
    }
  }
#pragma unroll
  for (int j = 0; j < REF; ++j) enc[j] = fast_tanh(enc[j]);

  // ---------------- Phase C: corr -------------------------------------------
  float corr[CS];
#pragma unroll
  for (int i = 0; i < CS; ++i) corr[i] = b_c2[i];

  float rr[REF];
  if (!USE_WS) {
#pragma unroll
    for (int k = 0; k < REF; ++k) rr[k] = policy ? ref_p[k] : ref_m[k];
  }

#pragma unroll 1
  for (int j = 0; j < HID; ++j) {
    float acc;
    if (USE_WS) {
      acc = policy ? ws[4096 + j] : ws[4160 + j];
#pragma unroll
      for (int k = 0; k < REF; ++k) acc = fmaf(enc[k], ws[3072 + j * REF + k], acc);
    } else {
      acc = b_c1[j];
#pragma unroll
      for (int k = 0; k < REF; ++k) {
        acc = fmaf(enc[k], w_c1[j * 48 + k], acc);
        acc = fmaf(rr[k], w_c1[j * 48 + 16 + k], acc);
        acc = fmaf(enc[k] - rr[k], w_c1[j * 48 + 32 + k], acc);
      }
    }
    const float h = fast_tanh(acc);
#pragma unroll
    for (int i = 0; i < CS; ++i) {
      const float w = USE_WS ? ws[4224 + j * 64 + i] : w_c2[i * 64 + j];
      corr[i] = fmaf(w, h, corr[i]);
    }
  }

  // ---------------- Output ---------------------------------------------------
  const float csv = policy ? cs_p[0] : cs_m[0];
  const float esv = policy ? es_p[0] : es_m[0];
  const float* np_ = noise + off;
  float* op = out + off;
#pragma unroll
  for (int k4 = 0; k4 < CS / 4; ++k4) {
    const float4 n4 = *reinterpret_cast<const float4*>(np_ + 4 * k4);
    float4 o;
#pragma unroll
    for (int c = 0; c < 4; ++c) {
      const int k = 4 * k4 + c;
      float cv = fast_tanh(corr[k]) * csv;
      cv = fminf(fmaxf(cv, -0.1f), 0.1f);
      const float v = base[k] + cv + get4(n4, c) * esv;
      if (c == 0) o.x = v;
      else if (c == 1) o.y = v;
      else if (c == 2) o.z = v;
      else o.w = v;
    }
    *reinterpret_cast<float4*>(op + 4 * k4) = o;
  }
}

extern "C" void kernel_launch(void* const* d_in, const int* in_sizes, int n_in,
                              void* d_out, int out_size, void* d_ws, size_t ws_size,
                              hipStream_t stream) {
  const float* A     = (const float*)d_in[0];
  const float* B     = (const float*)d_in[1];
  const int*   coord = (const int*)d_in[2];
  const float* noise = (const float*)d_in[3];
  const float* w_enc = (const float*)d_in[4];
  const float* b_enc = (const float*)d_in[5];
  const float* w_c1  = (const float*)d_in[6];
  const float* b_c1  = (const float*)d_in[7];
  const float* w_c2  = (const float*)d_in[8];
  const float* b_c2  = (const float*)d_in[9];
  const float* w_g1  = (const float*)d_in[10];
  const float* b_g1  = (const float*)d_in[11];
  const float* w_g2  = (const float*)d_in[12];
  const float* b_g2  = (const float*)d_in[13];
  const float* ref_p = (const float*)d_in[14];
  const float* ref_m = (const float*)d_in[15];
  const float* cs_p  = (const float*)d_in[16];
  const float* cs_m  = (const float*)d_in[17];
  const float* es_p  = (const float*)d_in[18];
  const float* es_m  = (const float*)d_in[19];
  float* out = (float*)d_out;
  float* ws  = (float*)d_ws;

  const bool use_ws = ws_size >= WS_FLOATS * sizeof(float);
  const int blocks = NC / 256;

  if (use_ws) {
    setup_fold_kernel<<<1, 256, 0, stream>>>(w_g1, w_c1, b_c1, w_c2, ref_p, ref_m, ws);
    dual_mutate_kernel<true><<<blocks, 256, 0, stream>>>(
        A, B, coord, noise, w_enc, b_enc, w_c1, b_c1, w_c2, b_c2, w_g1, b_g1,
        w_g2, b_g2, ref_p, ref_m, cs_p, cs_m, es_p, es_m, ws, out);
  } else {
    dual_mutate_kernel<false><<<blocks, 256, 0, stream>>>(
        A, B, coord, noise, w_enc, b_enc, w_c1, b_c1, w_c2, b_c2, w_g1, b_g1,
        w_g2, b_g2, ref_p, ref_m, cs_p, cs_m, es_p, es_m, ws, out);
  }
}